// Round 14
// baseline (22.965 us; speedup 1.0000x reference)
//
#include <hip/hip_runtime.h>
#include <math.h>

#define BB 32
#define LL 512
#define HH 352
#define WW 1216
#define NLINES (BB * LL)            // 16384
#define LPW 4                       // lines per wave
#define NBLK4 (NLINES / (LPW * 4))  // 1024 blocks, 4 waves each

typedef float f4 __attribute__((ext_vector_type(4), aligned(4)));

__device__ __forceinline__ float line_degree(int x0, int y0, int x1, int y1) {
    // Replicates: slopes = |(y1f - y0f) / (x1f - x0f + 1e-6)|
    //             degrees = (arctan(slopes) * 180.0 / pi) % 90.0
    float slope = fabsf(((float)y1 - (float)y0) / ((float)x1 - (float)x0 + 1e-6f));
    float deg = (atanf(slope) * 180.0f) / 3.14159274101257324f;  // f32(pi)
    return fmodf(deg, 90.0f);
}

__device__ __forceinline__ float walk_line(const float* __restrict__ p, int lane,
        int x0, int y0, int x1, int y1) {
    int dx = abs(x1 - x0), dy = abs(y1 - y0);
    bool xm = dx > dy;
    int dmaj = xm ? dx : dy;
    int dmin = xm ? dy : dx;
    float s = 0.0f;
    if (dy == 0) {
        // ---- Horizontal (~51% of lines): 1 f4 load per lane per 255-pair
        // chunk; 3 internal diffs + 1 cross-lane diff, per-pair masks. ----
        int base = y0 * WW + min(x0, x1);
        int dxs = dmaj;                          // number of pairs
        int nch = (dxs + 254) / 255;
        for (int j = 0; j < nch; ++j) {
            int pi0 = j * 255 + (lane << 2);     // first pair idx this lane
            int f0 = base + pi0;
            int fc = min(f0, HH * WW - 4);       // stay inside batch image
            f4 v = *(const f4*)(p + fc);
            float nx = __shfl_down(v.x, 1);      // next lane's first float
            float d0 = fabsf(v.y - v.x);
            float d1 = fabsf(v.z - v.y);
            float d2 = fabsf(v.w - v.z);
            float d3 = fabsf(nx - v.w);
            s += (pi0     < dxs) ? d0 : 0.0f;
            s += (pi0 + 1 < dxs) ? d1 : 0.0f;
            s += (pi0 + 2 < dxs) ? d2 : 0.0f;
            s += (pi0 + 3 < dxs && lane < 63) ? d3 : 0.0f;
        }
    } else {
        // ---- General scattered path (sloped / vertical lines) ----
        int sx = (x1 > x0) - (x1 < x0);
        int sy = (y1 > y0) - (y1 < y0);
        int smaj = xm ? sx : sy;
        int smin = xm ? sy : sx;
        int maj0 = xm ? x0 : y0;
        int min0 = xm ? y0 : x0;
        unsigned den = 2u * (unsigned)dmaj;
        int tdm = 2 * dmin;
        // Wave-uniform magic reciprocal: exact floor(num/den) for num < 2^22.
        unsigned M = 0xFFFFFFFFu / den + 1u;
        int sA = xm ? 1 : WW;
        int sB = xm ? WW : 1;
        int A = smaj * sA;
        int Bm = smin * sB;
        int off0 = maj0 * sA + min0 * sB;
        // 63-point chunks; idc-clamp repeats the endpoint (diff 0) past end.
        int niter = (dmaj + 62) / 63;
        int nbatch = (niter + 7) >> 3;
        int idx = lane;
        for (int t = 0; t < nbatch; ++t, idx += 504) {
            int offs[8];
            #pragma unroll
            for (int k = 0; k < 8; ++k) {
                int idc = min(idx + 63 * k, dmaj);
                unsigned num = (unsigned)(tdm * idc) + (unsigned)dmaj;
                unsigned q = __umulhi(num, M);
                q -= (q * den > num) ? 1u : 0u;
                offs[k] = off0 + idc * A + (int)q * Bm;
            }
            float v[8];
            #pragma unroll
            for (int k = 0; k < 8; ++k) v[k] = p[offs[k]];
            #pragma unroll
            for (int k = 0; k < 8; ++k) {
                float vn = __shfl_down(v[k], 1);
                float d = fabsf(vn - v[k]);
                s += (lane < 63) ? d : 0.0f;
            }
        }
    }
    return s;
}

// Unweighted diff-sums, 4 lines per wave: one preamble latency round for all
// 4 descriptors + 8 endpoints, then 4 sequential walk bodies (R13 showed
// merging the gather rounds regresses; sequential with early-out is best).
__global__ void __launch_bounds__(256) line_walk_kernel(
        const float* __restrict__ pred, const int* __restrict__ lines,
        float* __restrict__ partials, unsigned* __restrict__ counter) {
    if (blockIdx.x == 0 && threadIdx.x == 0) *counter = 0;  // reset for finalize
    int lane = threadIdx.x & 63;
    int w = threadIdx.x >> 6;
    // XCD-aware swizzle: each XCD gets a contiguous chunk of lines.
    int bid = blockIdx.x;
    int swz = (bid & 7) * (NBLK4 / 8) + (bid >> 3);
    int W = swz * 4 + w;                 // wave id
    int g0 = W * LPW;
    int b = g0 >> 9;                     // all 4 lines in same batch (LL%4==0)

    int x0[LPW], y0[LPW], x1[LPW], y1[LPW];
    #pragma unroll
    for (int i = 0; i < LPW; ++i) {
        int4 ln = ((const int4*)lines)[g0 + i];
        x0[i] = min(max(ln.x, 0), WW - 1);
        y0[i] = min(max(ln.y, 0), HH - 1);
        x1[i] = min(max(ln.z, 0), WW - 1);
        y1[i] = min(max(ln.w, 0), HH - 1);
    }

    const float* __restrict__ p = pred + (size_t)b * (HH * WW);

    // All 8 endpoint loads issue together (one latency round for 4 lines).
    float vf[LPW], vl[LPW];
    #pragma unroll
    for (int i = 0; i < LPW; ++i) {
        vf[i] = p[y0[i] * WW + x0[i]];
        vl[i] = p[y1[i] * WW + x1[i]];
    }

    bool act[LPW];
    float s[LPW];
    #pragma unroll
    for (int i = 0; i < LPW; ++i) {
        int dmaj = max(abs(x1[i] - x0[i]), abs(y1[i] - y0[i]));
        // Early-out: reference zeroes diff_sums when |vf - vl| < 0.5 (~28%).
        act[i] = (fabsf(vf[i] - vl[i]) >= 0.5f) && (dmaj > 0);
    }
    #pragma unroll
    for (int i = 0; i < LPW; ++i) {
        s[i] = act[i] ? walk_line(p, lane, x0[i], y0[i], x1[i], y1[i]) : 0.0f;
    }

    // Interleaved wave reductions (dependency chains overlap).
    #pragma unroll
    for (int off = 32; off > 0; off >>= 1) {
        #pragma unroll
        for (int i = 0; i < LPW; ++i) s[i] += __shfl_down(s[i], off);
    }
    if (lane == 0) {
        #pragma unroll
        for (int i = 0; i < LPW; ++i) partials[g0 + i] = act[i] ? s[i] : 0.0f;
    }
}

// Degree + per-batch max + weight + weighted block-sum; last block writes out.
// powf chains strength-reduced: d^1.5 = d*sqrt(d); (t^2.5)^0.4 = t;
// x^4 = sq(sq(x)). Deviation vs libm powf ~1e-5 relative (threshold 112).
__global__ void finalize_kernel(const int* __restrict__ lines,
                                const float* __restrict__ partials,
                                float* __restrict__ bsum,
                                unsigned* __restrict__ counter,
                                float* __restrict__ out) {
    __shared__ float red[LL];
    int b = blockIdx.x;
    int t = threadIdx.x;
    int g = b * LL + t;
    int4 ln = ((const int4*)lines)[g];
    int x0 = min(max(ln.x, 0), WW - 1);
    int y0 = min(max(ln.y, 0), HH - 1);
    int x1 = min(max(ln.z, 0), WW - 1);
    int y1 = min(max(ln.w, 0), HH - 1);
    float deg = line_degree(x0, y0, x1, y1);
    red[t] = deg;
    __syncthreads();
    for (int s = LL / 2; s > 0; s >>= 1) {
        if (t < s) red[t] = fmaxf(red[t], red[t + s]);
        __syncthreads();
    }
    float mxv = red[0];
    __syncthreads();
    float skewed = (deg * sqrtf(deg)) / sqrtf(mxv + 1.0f);
    float tt = fabsf(skewed - 45.0f);
    float h = 90.0f - tt;                    // == 90 - (tt^2.5)^0.4
    float hw = h * (1.0f / 300.0f);
    float hw2 = hw * hw;
    float wgt = hw2 * hw2;                   // (h/300)^4
    red[t] = wgt * partials[g];
    __syncthreads();
    for (int s = LL / 2; s > 0; s >>= 1) {
        if (t < s) red[t] += red[t + s];
        __syncthreads();
    }
    if (t == 0) {
        bsum[b] = red[0];
        __threadfence();                     // release bsum before counter bump
        if (atomicAdd(counter, 1u) == BB - 1) {
            __threadfence();                 // acquire others' bsum
            float tot = 0.0f;
            #pragma unroll
            for (int i = 0; i < BB; ++i) tot += bsum[i];  // fixed order: deterministic
            out[0] = tot;
        }
    }
}

extern "C" void kernel_launch(void* const* d_in, const int* in_sizes, int n_in,
                              void* d_out, int out_size, void* d_ws, size_t ws_size,
                              hipStream_t stream) {
    const float* pred = (const float*)d_in[0];
    const int* lines = (const int*)d_in[1];
    float* out = (float*)d_out;
    float* ws = (float*)d_ws;
    float* partials = ws;                    // 16384 floats
    float* bsum = ws + NLINES;               // 32 floats
    unsigned* counter = (unsigned*)(ws + NLINES + BB);  // 1 uint

    line_walk_kernel<<<NBLK4, 256, 0, stream>>>(pred, lines, partials, counter);
    finalize_kernel<<<BB, LL, 0, stream>>>(lines, partials, bsum, counter, out);
}

// Round 15
// 20.684 us; speedup vs baseline: 1.1103x; 1.1103x over previous
//
#include <hip/hip_runtime.h>
#include <math.h>

#define BB 32
#define LL 512
#define HH 352
#define WW 1216
#define NLINES (BB * LL)          // 16384
#define LPW 2                     // lines per wave (R12 sweet spot: 8 waves/SIMD)
#define NBLK2 (NLINES / (LPW * 4))  // 2048 blocks, 4 waves each

typedef float f4 __attribute__((ext_vector_type(4), aligned(4)));

__device__ __forceinline__ float line_degree(int x0, int y0, int x1, int y1) {
    // Replicates: slopes = |(y1f - y0f) / (x1f - x0f + 1e-6)|
    //             degrees = (arctan(slopes) * 180.0 / pi) % 90.0
    float slope = fabsf(((float)y1 - (float)y0) / ((float)x1 - (float)x0 + 1e-6f));
    float deg = (atanf(slope) * 180.0f) / 3.14159274101257324f;  // f32(pi)
    return fmodf(deg, 90.0f);
}

__device__ __forceinline__ float walk_line(const float* __restrict__ p, int lane,
        int x0, int y0, int x1, int y1) {
    int dx = abs(x1 - x0), dy = abs(y1 - y0);
    bool xm = dx > dy;
    int dmaj = xm ? dx : dy;
    int dmin = xm ? dy : dx;
    float s = 0.0f;
    if (dy == 0) {
        // ---- Horizontal (~51% of lines): 1 f4 load per lane per 255-pair
        // chunk; 3 internal diffs + 1 cross-lane diff, per-pair masks. ----
        int base = y0 * WW + min(x0, x1);
        int dxs = dmaj;                          // number of pairs
        int nch = (dxs + 254) / 255;
        for (int j = 0; j < nch; ++j) {
            int pi0 = j * 255 + (lane << 2);     // first pair idx this lane
            int f0 = base + pi0;
            int fc = min(f0, HH * WW - 4);       // stay inside batch image
            f4 v = *(const f4*)(p + fc);
            float nx = __shfl_down(v.x, 1);      // next lane's first float
            float d0 = fabsf(v.y - v.x);
            float d1 = fabsf(v.z - v.y);
            float d2 = fabsf(v.w - v.z);
            float d3 = fabsf(nx - v.w);
            s += (pi0     < dxs) ? d0 : 0.0f;
            s += (pi0 + 1 < dxs) ? d1 : 0.0f;
            s += (pi0 + 2 < dxs) ? d2 : 0.0f;
            s += (pi0 + 3 < dxs && lane < 63) ? d3 : 0.0f;
        }
    } else {
        // ---- General scattered path (sloped / vertical lines) ----
        int sx = (x1 > x0) - (x1 < x0);
        int sy = (y1 > y0) - (y1 < y0);
        int smaj = xm ? sx : sy;
        int smin = xm ? sy : sx;
        int maj0 = xm ? x0 : y0;
        int min0 = xm ? y0 : x0;
        unsigned den = 2u * (unsigned)dmaj;
        int tdm = 2 * dmin;
        // Wave-uniform magic reciprocal: exact floor(num/den) for num < 2^22.
        unsigned M = 0xFFFFFFFFu / den + 1u;
        int sA = xm ? 1 : WW;
        int sB = xm ? WW : 1;
        int A = smaj * sA;
        int Bm = smin * sB;
        int off0 = maj0 * sA + min0 * sB;
        // 63-point chunks; idc-clamp repeats the endpoint (diff 0) past end.
        int niter = (dmaj + 62) / 63;
        int nbatch = (niter + 7) >> 3;
        int idx = lane;
        for (int t = 0; t < nbatch; ++t, idx += 504) {
            int offs[8];
            #pragma unroll
            for (int k = 0; k < 8; ++k) {
                int idc = min(idx + 63 * k, dmaj);
                unsigned num = (unsigned)(tdm * idc) + (unsigned)dmaj;
                unsigned q = __umulhi(num, M);
                q -= (q * den > num) ? 1u : 0u;
                offs[k] = off0 + idc * A + (int)q * Bm;
            }
            float v[8];
            #pragma unroll
            for (int k = 0; k < 8; ++k) v[k] = p[offs[k]];
            #pragma unroll
            for (int k = 0; k < 8; ++k) {
                float vn = __shfl_down(v[k], 1);
                float d = fabsf(vn - v[k]);
                s += (lane < 63) ? d : 0.0f;
            }
        }
    }
    return s;
}

// Unweighted diff-sums, 2 lines per wave (amortized preamble, full occupancy).
__global__ void __launch_bounds__(256) line_walk_kernel(
        const float* __restrict__ pred, const int* __restrict__ lines,
        float* __restrict__ partials, unsigned* __restrict__ counter) {
    if (blockIdx.x == 0 && threadIdx.x == 0) *counter = 0;  // reset for finalize
    int lane = threadIdx.x & 63;
    int w = threadIdx.x >> 6;
    // XCD-aware swizzle: each XCD gets a contiguous chunk of lines.
    int bid = blockIdx.x;
    int swz = (bid & 7) * (NBLK2 / 8) + (bid >> 3);
    int W = swz * 4 + w;                 // wave id
    int g0 = W * LPW, g1 = g0 + 1;
    int b = g0 >> 9;                     // both lines in same batch (LL even)

    int4 lA = ((const int4*)lines)[g0];
    int4 lB = ((const int4*)lines)[g1];
    int ax0 = min(max(lA.x, 0), WW - 1), ay0 = min(max(lA.y, 0), HH - 1);
    int ax1 = min(max(lA.z, 0), WW - 1), ay1 = min(max(lA.w, 0), HH - 1);
    int bx0 = min(max(lB.x, 0), WW - 1), by0 = min(max(lB.y, 0), HH - 1);
    int bx1 = min(max(lB.z, 0), WW - 1), by1 = min(max(lB.w, 0), HH - 1);

    const float* __restrict__ p = pred + (size_t)b * (HH * WW);

    // All 4 endpoint loads issue together (one latency round for both lines).
    float vfA = p[ay0 * WW + ax0];
    float vlA = p[ay1 * WW + ax1];
    float vfB = p[by0 * WW + bx0];
    float vlB = p[by1 * WW + bx1];

    int admaj = max(abs(ax1 - ax0), abs(ay1 - ay0));
    int bdmaj = max(abs(bx1 - bx0), abs(by1 - by0));

    // Early-out: reference zeroes diff_sums when |vf - vl| < 0.5 (~28%).
    bool actA = (fabsf(vfA - vlA) >= 0.5f) && (admaj > 0);
    bool actB = (fabsf(vfB - vlB) >= 0.5f) && (bdmaj > 0);

    float s0 = actA ? walk_line(p, lane, ax0, ay0, ax1, ay1) : 0.0f;
    float s1 = actB ? walk_line(p, lane, bx0, by0, bx1, by1) : 0.0f;

    // Two interleaved wave reductions (dependency chains overlap).
    #pragma unroll
    for (int off = 32; off > 0; off >>= 1) {
        s0 += __shfl_down(s0, off);
        s1 += __shfl_down(s1, off);
    }
    if (lane == 0) {
        partials[g0] = actA ? s0 : 0.0f;
        partials[g1] = actB ? s1 : 0.0f;
    }
}

// Degree + per-batch max + weight + weighted block-sum; last block writes out.
// Wave shfl reductions + one 8-slot LDS step (4 barriers, was ~18).
// powf chains strength-reduced: d^1.5 = d*sqrt(d); (t^2.5)^0.4 = t;
// x^4 = sq(sq(x)). Deviation vs libm powf ~1e-5 relative (threshold 112).
__global__ void finalize_kernel(const int* __restrict__ lines,
                                const float* __restrict__ partials,
                                float* __restrict__ bsum,
                                unsigned* __restrict__ counter,
                                float* __restrict__ out) {
    __shared__ float wred[8];
    __shared__ float bc;
    int b = blockIdx.x;
    int t = threadIdx.x;
    int lane = t & 63, wv = t >> 6;          // 8 waves of 64
    int g = b * LL + t;
    int4 ln = ((const int4*)lines)[g];
    int x0 = min(max(ln.x, 0), WW - 1);
    int y0 = min(max(ln.y, 0), HH - 1);
    int x1 = min(max(ln.z, 0), WW - 1);
    int y1 = min(max(ln.w, 0), HH - 1);
    float deg = line_degree(x0, y0, x1, y1);

    float m = deg;
    #pragma unroll
    for (int off = 32; off > 0; off >>= 1) m = fmaxf(m, __shfl_down(m, off));
    if (lane == 0) wred[wv] = m;
    __syncthreads();
    if (t == 0) {
        float mm = wred[0];
        #pragma unroll
        for (int i = 1; i < 8; ++i) mm = fmaxf(mm, wred[i]);
        bc = mm;
    }
    __syncthreads();
    float mxv = bc;

    float skewed = (deg * sqrtf(deg)) / sqrtf(mxv + 1.0f);
    float tt = fabsf(skewed - 45.0f);
    float h = 90.0f - tt;                    // == 90 - (tt^2.5)^0.4
    float hw = h * (1.0f / 300.0f);
    float hw2 = hw * hw;
    float wgt = hw2 * hw2;                   // (h/300)^4
    float sv = wgt * partials[g];
    #pragma unroll
    for (int off = 32; off > 0; off >>= 1) sv += __shfl_down(sv, off);
    if (lane == 0) wred[wv] = sv;
    __syncthreads();
    if (t == 0) {
        float tot = 0.0f;
        #pragma unroll
        for (int i = 0; i < 8; ++i) tot += wred[i];
        bsum[b] = tot;
        __threadfence();                     // release bsum before counter bump
        if (atomicAdd(counter, 1u) == BB - 1) {
            __threadfence();                 // acquire others' bsum
            float acc = 0.0f;
            #pragma unroll
            for (int i = 0; i < BB; ++i) acc += bsum[i];  // fixed order: deterministic
            out[0] = acc;
        }
    }
}

extern "C" void kernel_launch(void* const* d_in, const int* in_sizes, int n_in,
                              void* d_out, int out_size, void* d_ws, size_t ws_size,
                              hipStream_t stream) {
    const float* pred = (const float*)d_in[0];
    const int* lines = (const int*)d_in[1];
    float* out = (float*)d_out;
    float* ws = (float*)d_ws;
    float* partials = ws;                    // 16384 floats
    float* bsum = ws + NLINES;               // 32 floats
    unsigned* counter = (unsigned*)(ws + NLINES + BB);  // 1 uint

    line_walk_kernel<<<NBLK2, 256, 0, stream>>>(pred, lines, partials, counter);
    finalize_kernel<<<BB, LL, 0, stream>>>(lines, partials, bsum, counter, out);
}